// Round 1
// baseline (7890.630 us; speedup 1.0000x reference)
//
#include <hip/hip_runtime.h>
#include <hip/hip_bf16.h>
#include <math.h>

#define BB 512
#define LATENT 128
#define HID 256
#define G3 768
#define NMAX 50
#define NHEADS 4
#define HD 64
#define NPAIRS 1225

// ---------------------------------------------------------------------------
// K1: xg0[b,t,g] = sum_i seq[b,t,i]*w_ih0[g,i] + b_ih0[g]
//     seq = (z[b,:]+pos[t,:]) masked by t < n_nodes[b]
// 8 rows (b,t) per block, 256 threads, thread g computes gates g, g+256, g+512
__global__ __launch_bounds__(256) void k_xg0(
        const float* __restrict__ z, const float* __restrict__ pos,
        const int* __restrict__ nn, const float* __restrict__ w,
        const float* __restrict__ bias, double* __restrict__ xg)
{
    const int row0 = blockIdx.x * 8;
    const int g = threadIdx.x;
    __shared__ double xs[8][LATENT];
    for (int idx = threadIdx.x; idx < 8 * LATENT; idx += 256) {
        int r = idx / LATENT, i = idx % LATENT;
        int row = row0 + r;
        int b = row / NMAX, t = row % NMAX;
        double v = 0.0;
        if (t < nn[b]) v = (double)z[b * LATENT + i] + (double)pos[t * LATENT + i];
        xs[r][i] = v;
    }
    __syncthreads();
    double a0[8], a1[8], a2[8];
    #pragma unroll
    for (int r = 0; r < 8; ++r) { a0[r] = 0.0; a1[r] = 0.0; a2[r] = 0.0; }
    for (int i = 0; i < LATENT; ++i) {
        double w0 = (double)w[g * LATENT + i];
        double w1v = (double)w[(g + HID) * LATENT + i];
        double w2v = (double)w[(g + 2 * HID) * LATENT + i];
        #pragma unroll
        for (int r = 0; r < 8; ++r) {
            double xv = xs[r][i];
            a0[r] += xv * w0; a1[r] += xv * w1v; a2[r] += xv * w2v;
        }
    }
    double b0 = (double)bias[g], b1 = (double)bias[g + HID], b2v = (double)bias[g + 2 * HID];
    #pragma unroll
    for (int r = 0; r < 8; ++r) {
        double* o = xg + (size_t)(row0 + r) * G3;
        o[g] = a0[r] + b0;
        o[g + HID] = a1[r] + b1;
        o[g + 2 * HID] = a2[r] + b2v;
    }
}

// ---------------------------------------------------------------------------
// K3: xg1[b,t,g] = sum_k h0[b,t,k]*w_ih1[g,k] + b_ih1[g]   (K=256, f64 input)
__global__ __launch_bounds__(256) void k_xg1(
        const double* __restrict__ hin, const float* __restrict__ w,
        const float* __restrict__ bias, double* __restrict__ xg)
{
    const int row0 = blockIdx.x * 8;
    const int g = threadIdx.x;
    __shared__ double xs[8][HID];
    for (int idx = threadIdx.x; idx < 8 * HID; idx += 256)
        xs[idx / HID][idx % HID] = hin[(size_t)row0 * HID + idx];
    __syncthreads();
    double a0[8], a1[8], a2[8];
    #pragma unroll
    for (int r = 0; r < 8; ++r) { a0[r] = 0.0; a1[r] = 0.0; a2[r] = 0.0; }
    for (int k = 0; k < HID; ++k) {
        double w0 = (double)w[g * HID + k];
        double w1v = (double)w[(g + HID) * HID + k];
        double w2v = (double)w[(g + 2 * HID) * HID + k];
        #pragma unroll
        for (int r = 0; r < 8; ++r) {
            double xv = xs[r][k];
            a0[r] += xv * w0; a1[r] += xv * w1v; a2[r] += xv * w2v;
        }
    }
    double b0 = (double)bias[g], b1 = (double)bias[g + HID], b2v = (double)bias[g + 2 * HID];
    #pragma unroll
    for (int r = 0; r < 8; ++r) {
        double* o = xg + (size_t)(row0 + r) * G3;
        o[g] = a0[r] + b0;
        o[g + HID] = a1[r] + b1;
        o[g + 2 * HID] = a2[r] + b2v;
    }
}

// ---------------------------------------------------------------------------
// K2: one GRU time step. grid=128 blocks x 4 batch rows, 256 threads.
// thread g computes feature g: needs w_hh rows g, g+256, g+512.
__global__ __launch_bounds__(256) void k_gru_step(
        const double* __restrict__ xg, double* __restrict__ hout,
        const float* __restrict__ whh, const float* __restrict__ bhh, int t)
{
    const int b0 = blockIdx.x * 4;
    const int g = threadIdx.x;
    __shared__ double hs[4][HID];
    if (t == 0) {
        for (int idx = threadIdx.x; idx < 4 * HID; idx += 256)
            hs[idx / HID][idx % HID] = 0.0;
    } else {
        for (int idx = threadIdx.x; idx < 4 * HID; idx += 256) {
            int sb = idx / HID, k = idx % HID;
            hs[sb][k] = hout[((size_t)(b0 + sb) * NMAX + (t - 1)) * HID + k];
        }
    }
    __syncthreads();
    double ar[4] = {0, 0, 0, 0}, az[4] = {0, 0, 0, 0}, an[4] = {0, 0, 0, 0};
    for (int k = 0; k < HID; ++k) {
        double wr = (double)whh[g * HID + k];
        double wz = (double)whh[(g + HID) * HID + k];
        double wn = (double)whh[(g + 2 * HID) * HID + k];
        #pragma unroll
        for (int sb = 0; sb < 4; ++sb) {
            double hk = hs[sb][k];
            ar[sb] += hk * wr; az[sb] += hk * wz; an[sb] += hk * wn;
        }
    }
    double br = (double)bhh[g], bz = (double)bhh[g + HID], bn = (double)bhh[g + 2 * HID];
    #pragma unroll
    for (int sb = 0; sb < 4; ++sb) {
        int b = b0 + sb;
        const double* x = xg + ((size_t)b * NMAX + t) * G3;
        double xr = x[g], xz = x[g + HID], xn = x[g + 2 * HID];
        double hr = ar[sb] + br, hz = az[sb] + bz, hn = an[sb] + bn;
        double r = 1.0 / (1.0 + exp(-(xr + hr)));
        double zt = 1.0 / (1.0 + exp(-(xz + hz)));
        double n = tanh(xn + r * hn);
        double hnew = (1.0 - zt) * n + zt * hs[sb][g];
        hout[((size_t)b * NMAX + t) * HID + g] = hnew;
    }
}

// ---------------------------------------------------------------------------
// c[k] = sum_m attn_out_b[m]*mlp_w1[k,m] + mlp_b1[k]
__global__ void k_const(const float* __restrict__ ob, const float* __restrict__ w1,
                        const float* __restrict__ b1, double* __restrict__ c)
{
    int k = threadIdx.x;
    double acc = 0.0;
    for (int m = 0; m < HID; ++m) acc += (double)ob[m] * (double)w1[k * HID + m];
    c[k] = acc + (double)b1[k];
}

// ---------------------------------------------------------------------------
// K5a: node_emb[b,n,o] = sum_h (mask? h1[b,n,h]:0) * proj[o,h]   -> f32
__global__ __launch_bounds__(256) void k_nodeemb(
        const double* __restrict__ h1, const int* __restrict__ nn,
        const float* __restrict__ proj, float* __restrict__ ne)
{
    const int row0 = blockIdx.x * 8;
    const int g = threadIdx.x;
    __shared__ double xs[8][HID];
    for (int idx = threadIdx.x; idx < 8 * HID; idx += 256) {
        int r = idx / HID, i = idx % HID;
        int row = row0 + r;
        int b = row / NMAX, n = row % NMAX;
        xs[r][i] = (n < nn[b]) ? h1[(size_t)row * HID + i] : 0.0;
    }
    __syncthreads();
    double acc[8];
    #pragma unroll
    for (int r = 0; r < 8; ++r) acc[r] = 0.0;
    for (int k = 0; k < HID; ++k) {
        double w = (double)proj[g * HID + k];
        #pragma unroll
        for (int r = 0; r < 8; ++r) acc[r] += xs[r][k] * w;
    }
    #pragma unroll
    for (int r = 0; r < 8; ++r) ne[(size_t)(row0 + r) * HID + g] = (float)acc[r];
}

// ---------------------------------------------------------------------------
// K5b: Q/K/V[b,n,:] = ne @ {wq,wk,wv}.T + {bq,bk,bv}   -> f32
__global__ __launch_bounds__(256) void k_qkv(
        const float* __restrict__ ne, const float* __restrict__ wi,
        const float* __restrict__ bi, float* __restrict__ Q,
        float* __restrict__ Kb, float* __restrict__ V)
{
    const int row0 = blockIdx.x * 8;
    const int g = threadIdx.x;
    __shared__ float xs[8][HID];
    for (int idx = threadIdx.x; idx < 8 * HID; idx += 256)
        xs[idx / HID][idx % HID] = ne[(size_t)row0 * HID + idx];
    __syncthreads();
    double aq[8], ak[8], av[8];
    #pragma unroll
    for (int r = 0; r < 8; ++r) { aq[r] = 0.0; ak[r] = 0.0; av[r] = 0.0; }
    for (int k = 0; k < HID; ++k) {
        double wq = (double)wi[g * HID + k];
        double wk = (double)wi[(g + HID) * HID + k];
        double wv = (double)wi[(g + 2 * HID) * HID + k];
        #pragma unroll
        for (int r = 0; r < 8; ++r) {
            double x = (double)xs[r][k];
            aq[r] += x * wq; ak[r] += x * wk; av[r] += x * wv;
        }
    }
    double bq = (double)bi[g], bk = (double)bi[g + HID], bv = (double)bi[g + 2 * HID];
    #pragma unroll
    for (int r = 0; r < 8; ++r) {
        size_t o = (size_t)(row0 + r) * HID + g;
        Q[o] = (float)(aq[r] + bq);
        Kb[o] = (float)(ak[r] + bk);
        V[o] = (float)(av[r] + bv);
    }
}

// ---------------------------------------------------------------------------
// K5c: VW[r][h][m] = sum_d V[r][h*64+d]*wo[m, h*64+d];  G[r][h][k] = sum_m VW*w1[k,m]
__global__ __launch_bounds__(256) void k_g(
        const float* __restrict__ V, const float* __restrict__ wo,
        const float* __restrict__ w1, float* __restrict__ G)
{
    const int row0 = blockIdx.x * 8;
    const int tid = threadIdx.x;
    __shared__ float vs[8][HID];
    __shared__ float vw[8][NHEADS][HID];
    for (int idx = tid; idx < 8 * HID; idx += 256)
        vs[idx / HID][idx % HID] = V[(size_t)row0 * HID + idx];
    __syncthreads();
    // step 1: VW, thread = m
    for (int h = 0; h < NHEADS; ++h) {
        double acc[8];
        #pragma unroll
        for (int r = 0; r < 8; ++r) acc[r] = 0.0;
        for (int d = 0; d < HD; ++d) {
            double w = (double)wo[tid * HID + h * HD + d];
            #pragma unroll
            for (int r = 0; r < 8; ++r) acc[r] += (double)vs[r][h * HD + d] * w;
        }
        #pragma unroll
        for (int r = 0; r < 8; ++r) vw[r][h][tid] = (float)acc[r];
    }
    __syncthreads();
    // step 2: G, thread = k
    double acc2[8][NHEADS];
    #pragma unroll
    for (int r = 0; r < 8; ++r)
        #pragma unroll
        for (int h = 0; h < NHEADS; ++h) acc2[r][h] = 0.0;
    for (int m = 0; m < HID; ++m) {
        double w = (double)w1[tid * HID + m];
        #pragma unroll
        for (int r = 0; r < 8; ++r)
            #pragma unroll
            for (int h = 0; h < NHEADS; ++h) acc2[r][h] += (double)vw[r][h][m] * w;
    }
    #pragma unroll
    for (int r = 0; r < 8; ++r)
        #pragma unroll
        for (int h = 0; h < NHEADS; ++h)
            G[(((size_t)(row0 + r)) * NHEADS + h) * HID + tid] = (float)acc2[r][h];
}

// ---------------------------------------------------------------------------
// K7: one block per (b,i); loop j=i+1..nn-1. 4 waves = 4 heads for score dots.
// pre_k = c[k] + sum_h a0h*G[b,i,h,k] + a1h*G[b,j,h,k]; d = sum relu(pre)*w2d + b2d + g0-g1
__global__ __launch_bounds__(256) void k_pairs(
        const float* __restrict__ Q, const float* __restrict__ K,
        const float* __restrict__ G, const double* __restrict__ c,
        const int* __restrict__ nn, const float* __restrict__ gum,
        const float* __restrict__ w2, const float* __restrict__ b2,
        float* __restrict__ adj)
{
    const int bi = blockIdx.x;
    const int b = bi / (NMAX - 1);
    const int i = bi % (NMAX - 1);
    const int nnb = nn[b];
    if (i >= nnb - 1) return;
    const int tid = threadIdx.x;
    const int lane = tid & 63;
    const int wave = tid >> 6;
    __shared__ float qi[HID], ki[HID], gi[NHEADS][HID];
    __shared__ double s0sh[NHEADS], a0sh[NHEADS], a1sh[NHEADS];
    __shared__ double w2d[HID], csh[HID], dred[4];
    const size_t rowi = (size_t)b * NMAX + i;
    qi[tid] = Q[rowi * HID + tid];
    ki[tid] = K[rowi * HID + tid];
    #pragma unroll
    for (int h = 0; h < NHEADS; ++h) gi[h][tid] = G[(rowi * NHEADS + h) * HID + tid];
    w2d[tid] = (double)w2[tid] - (double)w2[HID + tid];
    csh[tid] = c[tid];
    __syncthreads();
    {   // s0 per head (same for all j)
        int h = wave;
        double p = (double)qi[h * HD + lane] * (double)ki[h * HD + lane];
        for (int off = 32; off; off >>= 1) p += __shfl_down(p, off, 64);
        if (lane == 0) s0sh[h] = p * 0.125;
    }
    __syncthreads();
    const double b2d = (double)b2[0] - (double)b2[1];
    for (int j = i + 1; j < nnb; ++j) {
        const size_t rowj = (size_t)b * NMAX + j;
        {
            int h = wave;
            double p = (double)qi[h * HD + lane] * (double)K[rowj * HID + h * HD + lane];
            for (int off = 32; off; off >>= 1) p += __shfl_down(p, off, 64);
            if (lane == 0) {
                double s0 = s0sh[h], s1 = p * 0.125;
                double mx = fmax(s0, s1);
                double e0 = exp(s0 - mx), e1 = exp(s1 - mx);
                double inv = 1.0 / (e0 + e1);
                a0sh[h] = e0 * inv; a1sh[h] = e1 * inv;
            }
        }
        __syncthreads();
        double pre = csh[tid];
        #pragma unroll
        for (int hh = 0; hh < NHEADS; ++hh) {
            pre += a0sh[hh] * (double)gi[hh][tid];
            pre += a1sh[hh] * (double)G[(rowj * NHEADS + hh) * HID + tid];
        }
        double hidv = pre > 0.0 ? pre : 0.0;
        double part = hidv * w2d[tid];
        for (int off = 32; off; off >>= 1) part += __shfl_down(part, off, 64);
        if (lane == 0) dred[wave] = part;
        __syncthreads();
        if (tid == 0) {
            double d = dred[0] + dred[1] + dred[2] + dred[3] + b2d;
            int p_idx = i * (2 * NMAX - i - 1) / 2 + (j - i - 1);
            const float* gp = gum + ((size_t)b * NPAIRS + p_idx) * 2;
            d += (double)gp[0] - (double)gp[1];
            if (d >= 0.0) {
                adj[(size_t)b * NMAX * NMAX + i * NMAX + j] = 1.0f;
                adj[(size_t)b * NMAX * NMAX + j * NMAX + i] = 1.0f;
            }
        }
        __syncthreads();
    }
}

__global__ void k_ws_too_small(float* adj) { adj[0] = 2.0f; }

// ---------------------------------------------------------------------------
extern "C" void kernel_launch(void* const* d_in, const int* in_sizes, int n_in,
                              void* d_out, int out_size, void* d_ws, size_t ws_size,
                              hipStream_t stream)
{
    const float* z          = (const float*)d_in[0];
    const int*   nn         = (const int*)d_in[1];
    const float* pos        = (const float*)d_in[3];
    const float* w_ih0      = (const float*)d_in[4];
    const float* w_hh0      = (const float*)d_in[5];
    const float* b_ih0      = (const float*)d_in[6];
    const float* b_hh0      = (const float*)d_in[7];
    const float* w_ih1      = (const float*)d_in[8];
    const float* w_hh1      = (const float*)d_in[9];
    const float* b_ih1      = (const float*)d_in[10];
    const float* b_hh1      = (const float*)d_in[11];
    const float* proj       = (const float*)d_in[12];
    const float* attn_in_w  = (const float*)d_in[13];
    const float* attn_in_b  = (const float*)d_in[14];
    const float* attn_out_w = (const float*)d_in[15];
    const float* attn_out_b = (const float*)d_in[16];
    const float* mlp_w1     = (const float*)d_in[17];
    const float* mlp_b1     = (const float*)d_in[18];
    const float* mlp_w2     = (const float*)d_in[19];
    const float* mlp_b2     = (const float*)d_in[20];
    const float* gum        = (const float*)d_in[21];

    float* adj = (float*)d_out;
    hipMemsetAsync(adj, 0, (size_t)out_size * sizeof(float), stream);

    // workspace layout (phase-aliased):
    //  region A [0,157286400): xg (f64) during GRU; then Q(26MB)+K(26MB)+G(105MB) f32
    //  region B [157286400,209715200): h0out f64; then c (f64, 2KB) + node_emb f32 @+4096
    //  region C [209715200,262144000): h1out f64; then V f32
    const size_t NEED = 262144000;
    if (ws_size < NEED) { hipLaunchKernelGGL(k_ws_too_small, dim3(1), dim3(1), 0, stream, adj); return; }

    char* ws = (char*)d_ws;
    double* xg  = (double*)(ws);
    double* h0o = (double*)(ws + 157286400);
    double* h1o = (double*)(ws + 209715200);
    float*  Q   = (float*)(ws);
    float*  Kb  = (float*)(ws + 26214400);
    float*  G   = (float*)(ws + 52428800);
    double* cbf = (double*)(ws + 157286400);
    float*  ne  = (float*)(ws + 157286400 + 4096);
    float*  V   = (float*)(ws + 209715200);

    const int ROWS = BB * NMAX;           // 25600
    const int RB = ROWS / 8;              // 3200 blocks

    hipLaunchKernelGGL(k_xg0, dim3(RB), dim3(256), 0, stream, z, pos, nn, w_ih0, b_ih0, xg);
    for (int t = 0; t < NMAX; ++t)
        hipLaunchKernelGGL(k_gru_step, dim3(BB / 4), dim3(256), 0, stream, xg, h0o, w_hh0, b_hh0, t);
    hipLaunchKernelGGL(k_xg1, dim3(RB), dim3(256), 0, stream, h0o, w_ih1, b_ih1, xg);
    for (int t = 0; t < NMAX; ++t)
        hipLaunchKernelGGL(k_gru_step, dim3(BB / 4), dim3(256), 0, stream, xg, h1o, w_hh1, b_hh1, t);

    hipLaunchKernelGGL(k_const, dim3(1), dim3(256), 0, stream, attn_out_b, mlp_w1, mlp_b1, cbf);
    hipLaunchKernelGGL(k_nodeemb, dim3(RB), dim3(256), 0, stream, h1o, nn, proj, ne);
    hipLaunchKernelGGL(k_qkv, dim3(RB), dim3(256), 0, stream, ne, attn_in_w, attn_in_b, Q, Kb, V);
    hipLaunchKernelGGL(k_g, dim3(RB), dim3(256), 0, stream, V, attn_out_w, mlp_w1, G);
    hipLaunchKernelGGL(k_pairs, dim3(BB * (NMAX - 1)), dim3(256), 0, stream,
                       Q, Kb, G, cbf, nn, gum, mlp_w2, mlp_b2, adj);
}

// Round 3
// 4039.101 us; speedup vs baseline: 1.9536x; 1.9536x over previous
//
#include <hip/hip_runtime.h>
#include <hip/hip_bf16.h>
#include <math.h>

#define BB 512
#define LATENT 128
#define HID 256
#define GDIM 768
#define NMAX 50
#define NHEADS 4
#define HD 64
#define NPAIRS 1225

// ---------------------------------------------------------------------------
// Generic tiled GEMM: O[r][o] = sum_k X[r][k] * W[o][k] (+bias[o])
// X: f64 or f32 (promoted), W: f32 (promoted), accumulate f64.
// Tile: 64 rows x 128 cols, 256 threads, thread tile 4x8. K multiple of 16.
// R fixed 25600 (grid.x=400), O = grid.y*128.
template<int KD, bool XF64, bool OF64, bool BIAS>
__global__ __launch_bounds__(256) void k_gemm(
        const void* __restrict__ Xv, long xstride,
        const float* __restrict__ W, int wstride, int wcol,
        const float* __restrict__ bias,
        void* __restrict__ Ov, long ostride, int ocol)
{
    __shared__ double xs[64][17];
    __shared__ float  wsm[128][17];
    const int rb = blockIdx.x * 64;
    const int ob = blockIdx.y * 128;
    const int tid = threadIdx.x;
    const int ty = tid >> 4, tx = tid & 15;
    const int lr  = tid >> 2;          // X tile row 0..63
    const int lk  = (tid & 3) * 4;     // X tile k   0,4,8,12
    const int lr2 = tid >> 1;          // W tile row 0..127
    const int lk2 = (tid & 1) * 8;     // W tile k   0,8

    double acc[4][8];
    #pragma unroll
    for (int i = 0; i < 4; ++i)
        #pragma unroll
        for (int j = 0; j < 8; ++j) acc[i][j] = 0.0;

    for (int k0 = 0; k0 < KD; k0 += 16) {
        if (XF64) {
            const double* X = (const double*)Xv + (size_t)(rb + lr) * xstride + k0 + lk;
            #pragma unroll
            for (int u = 0; u < 4; ++u) xs[lr][lk + u] = X[u];
        } else {
            const float* X = (const float*)Xv + (size_t)(rb + lr) * xstride + k0 + lk;
            #pragma unroll
            for (int u = 0; u < 4; ++u) xs[lr][lk + u] = (double)X[u];
        }
        {
            const float* Wp = W + (size_t)(ob + lr2) * wstride + wcol + k0 + lk2;
            #pragma unroll
            for (int u = 0; u < 8; ++u) wsm[lr2][lk2 + u] = Wp[u];
        }
        __syncthreads();
        #pragma unroll
        for (int kk = 0; kk < 16; ++kk) {
            double xr0 = xs[ty * 4 + 0][kk], xr1 = xs[ty * 4 + 1][kk];
            double xr2 = xs[ty * 4 + 2][kk], xr3 = xs[ty * 4 + 3][kk];
            #pragma unroll
            for (int j = 0; j < 8; ++j) {
                double w = (double)wsm[tx * 8 + j][kk];
                acc[0][j] += xr0 * w; acc[1][j] += xr1 * w;
                acc[2][j] += xr2 * w; acc[3][j] += xr3 * w;
            }
        }
        __syncthreads();
    }
    #pragma unroll
    for (int i = 0; i < 4; ++i) {
        size_t row = rb + ty * 4 + i;
        #pragma unroll
        for (int j = 0; j < 8; ++j) {
            int oc = ob + tx * 8 + j;
            double v = acc[i][j];
            if (BIAS) v += (double)bias[oc];
            if (OF64) ((double*)Ov)[row * ostride + ocol + oc] = v;
            else      ((float*)Ov)[row * ostride + ocol + oc] = (float)v;
        }
    }
}

// ---------------------------------------------------------------------------
// seq[row][i] = masked (z+pos) in f64
__global__ __launch_bounds__(256) void k_seq(
        const float* __restrict__ z, const float* __restrict__ pos,
        const int* __restrict__ nn, double* __restrict__ seq)
{
    int idx = blockIdx.x * 256 + threadIdx.x;     // 25600*128
    int row = idx >> 7, i = idx & 127;
    int b = row / NMAX, t = row % NMAX;
    seq[idx] = (t < nn[b]) ? (double)z[b * LATENT + i] + (double)pos[t * LATENT + i] : 0.0;
}

// h1m = masked h1
__global__ __launch_bounds__(256) void k_maskh(
        const double* __restrict__ h1, const int* __restrict__ nn,
        double* __restrict__ h1m)
{
    int idx = blockIdx.x * 256 + threadIdx.x;     // 25600*256
    int row = idx >> 8;
    int b = row / NMAX, n = row % NMAX;
    h1m[idx] = (n < nn[b]) ? h1[idx] : 0.0;
}

// pack w_hh [768][256] -> wP[fs(2)][k(256)][g(3)*128+ff]
__global__ __launch_bounds__(256) void k_pack(
        const float* __restrict__ whh, float* __restrict__ wP)
{
    int idx = blockIdx.x * 256 + threadIdx.x;     // 2*256*384 = 196608
    int fs = idx / 98304; int rem = idx % 98304;
    int k = rem / 384; int c = rem % 384;
    int g = c >> 7; int ff = c & 127;
    wP[idx] = whh[(size_t)(g * HID + fs * 128 + ff) * HID + k];
}

// ---------------------------------------------------------------------------
// GRU step, feature-sliced: grid 256 = 128 bgroups(4 rows) x 2 fslices(128 f).
// thread = r(4) x fp(64); handles features fp and fp+64 of its slice.
__global__ __launch_bounds__(256) void k_gru_step3(
        const double* __restrict__ xg, double* __restrict__ hout,
        const float* __restrict__ wP, const float* __restrict__ bhh, int t)
{
    const int bg = blockIdx.x >> 1;
    const int fs = blockIdx.x & 1;
    const int b0 = bg << 2;
    const int r  = threadIdx.x >> 6;
    const int fp = threadIdx.x & 63;
    const int f0 = fs * 128;
    __shared__ double hs[4][HID];
    __shared__ float  wt[64][384];
    for (int idx = threadIdx.x; idx < 4 * HID; idx += 256) {
        int rr = idx >> 8, k = idx & 255;
        hs[rr][k] = (t == 0) ? 0.0
                  : hout[((size_t)(b0 + rr) * NMAX + (t - 1)) * HID + k];
    }
    double a0 = 0, a1 = 0, a2 = 0, a3 = 0, a4 = 0, a5 = 0;
    for (int k0 = 0; k0 < HID; k0 += 64) {
        __syncthreads();
        {
            const float4* src = (const float4*)(wP + ((size_t)fs * 256 + k0) * 384);
            float4* dst = (float4*)&wt[0][0];
            #pragma unroll
            for (int u = 0; u < 24; ++u) dst[threadIdx.x + 256 * u] = src[threadIdx.x + 256 * u];
        }
        __syncthreads();
        #pragma unroll 8
        for (int kk = 0; kk < 64; ++kk) {
            double hk = hs[r][k0 + kk];
            a0 += hk * (double)wt[kk][fp];       a1 += hk * (double)wt[kk][fp + 64];
            a2 += hk * (double)wt[kk][128 + fp]; a3 += hk * (double)wt[kk][128 + fp + 64];
            a4 += hk * (double)wt[kk][256 + fp]; a5 += hk * (double)wt[kk][256 + fp + 64];
        }
    }
    const int b = b0 + r;
    const double* x = xg + ((size_t)b * NMAX + t) * GDIM;
    double* hp = hout + ((size_t)b * NMAX + t) * HID;
    double ag[6] = {a0, a1, a2, a3, a4, a5};
    #pragma unroll
    for (int e = 0; e < 2; ++e) {
        int ff = f0 + fp + e * 64;
        double hr = ag[0 + e] + (double)bhh[ff];
        double hz = ag[2 + e] + (double)bhh[HID + ff];
        double hn = ag[4 + e] + (double)bhh[2 * HID + ff];
        double rg = 1.0 / (1.0 + exp(-(x[ff] + hr)));
        double zg = 1.0 / (1.0 + exp(-(x[HID + ff] + hz)));
        double ng = tanh(x[2 * HID + ff] + rg * hn);
        hp[ff] = (1.0 - zg) * ng + zg * hs[r][ff];
    }
}

// ---------------------------------------------------------------------------
// c[k] = sum_m attn_out_b[m]*mlp_w1[k,m] + mlp_b1[k]
__global__ void k_const(const float* __restrict__ ob, const float* __restrict__ w1,
                        const float* __restrict__ b1, double* __restrict__ c)
{
    int k = threadIdx.x;
    double acc = 0.0;
    for (int m = 0; m < HID; ++m) acc += (double)ob[m] * (double)w1[k * HID + m];
    c[k] = acc + (double)b1[k];
}

// ---------------------------------------------------------------------------
// Pairs: block per (b,i); wave per j (stride 4). No block syncs in j-loop.
__global__ __launch_bounds__(256) void k_pairs2(
        const float* __restrict__ QKV, const float* __restrict__ Ga,
        const float* __restrict__ Gb, const float* __restrict__ Gc,
        const float* __restrict__ Gd, const double* __restrict__ c,
        const int* __restrict__ nn, const float* __restrict__ gum,
        const float* __restrict__ w2, const float* __restrict__ b2,
        float* __restrict__ adj)
{
    const int bi = blockIdx.x;
    const int b = bi / (NMAX - 1);
    const int i = bi % (NMAX - 1);
    const int nnb = nn[b];
    if (i >= nnb - 1) return;
    const int tid = threadIdx.x;
    const int lane = tid & 63;
    const int wave = tid >> 6;
    const size_t rowi = (size_t)b * NMAX + i;
    const float* Gp[4] = {Ga, Gb, Gc, Gd};

    // per-lane registers: its 4 k-slices (k = lane + 64q)
    double cw[4], w2r[4];
    float gir[4][4];
    #pragma unroll
    for (int q = 0; q < 4; ++q) {
        int k = lane + 64 * q;
        cw[q] = c[k];
        w2r[q] = (double)w2[k] - (double)w2[HID + k];
        #pragma unroll
        for (int h = 0; h < 4; ++h) gir[q][h] = Gp[h][rowi * HID + k];
    }
    // score lanes: h = lane>>4, dims (lane&15)*4..+3
    const int sh = lane >> 4, sd = (lane & 15) * 4;
    const float4 qv  = *(const float4*)&QKV[rowi * GDIM + sh * HD + sd];
    const float4 kv0 = *(const float4*)&QKV[rowi * GDIM + HID + sh * HD + sd];
    double s0 = (double)qv.x * kv0.x + (double)qv.y * kv0.y
              + (double)qv.z * kv0.z + (double)qv.w * kv0.w;
    #pragma unroll
    for (int m = 1; m < 16; m <<= 1) s0 += __shfl_xor(s0, m, 64);
    s0 *= 0.125;
    const double b2d = (double)b2[0] - (double)b2[1];

    for (int j = i + 1 + wave; j < nnb; j += 4) {
        const size_t rowj = (size_t)b * NMAX + j;
        const float4 kv = *(const float4*)&QKV[rowj * GDIM + HID + sh * HD + sd];
        double s1 = (double)qv.x * kv.x + (double)qv.y * kv.y
                  + (double)qv.z * kv.z + (double)qv.w * kv.w;
        #pragma unroll
        for (int m = 1; m < 16; m <<= 1) s1 += __shfl_xor(s1, m, 64);
        s1 *= 0.125;
        double mx = fmax(s0, s1);
        double e0 = exp(s0 - mx), e1 = exp(s1 - mx);
        double inv = 1.0 / (e0 + e1);
        double a0 = e0 * inv, a1 = e1 * inv;
        double a0h[4], a1h[4];
        #pragma unroll
        for (int h = 0; h < 4; ++h) {
            a0h[h] = __shfl(a0, h * 16, 64);
            a1h[h] = __shfl(a1, h * 16, 64);
        }
        double dsum = 0.0;
        #pragma unroll
        for (int q = 0; q < 4; ++q) {
            int k = lane + 64 * q;
            double pre = cw[q];
            #pragma unroll
            for (int h = 0; h < 4; ++h)
                pre += a0h[h] * (double)gir[q][h]
                     + a1h[h] * (double)Gp[h][rowj * HID + k];
            if (pre > 0.0) dsum += pre * w2r[q];
        }
        #pragma unroll
        for (int m = 1; m < 64; m <<= 1) dsum += __shfl_xor(dsum, m, 64);
        if (lane == 0) {
            int p_idx = i * (2 * NMAX - i - 1) / 2 + (j - i - 1);
            const float* gp = gum + ((size_t)b * NPAIRS + p_idx) * 2;
            double d = dsum + b2d + (double)gp[0] - (double)gp[1];
            if (d >= 0.0) {
                adj[(size_t)b * NMAX * NMAX + i * NMAX + j] = 1.0f;
                adj[(size_t)b * NMAX * NMAX + j * NMAX + i] = 1.0f;
            }
        }
    }
}

__global__ void k_ws_too_small(float* adj) { adj[0] = 2.0f; }

// ---------------------------------------------------------------------------
extern "C" void kernel_launch(void* const* d_in, const int* in_sizes, int n_in,
                              void* d_out, int out_size, void* d_ws, size_t ws_size,
                              hipStream_t stream)
{
    const float* z          = (const float*)d_in[0];
    const int*   nn         = (const int*)d_in[1];
    const float* pos        = (const float*)d_in[3];
    const float* w_ih0      = (const float*)d_in[4];
    const float* w_hh0      = (const float*)d_in[5];
    const float* b_ih0      = (const float*)d_in[6];
    const float* b_hh0      = (const float*)d_in[7];
    const float* w_ih1      = (const float*)d_in[8];
    const float* w_hh1      = (const float*)d_in[9];
    const float* b_ih1      = (const float*)d_in[10];
    const float* b_hh1      = (const float*)d_in[11];
    const float* proj       = (const float*)d_in[12];
    const float* attn_in_w  = (const float*)d_in[13];
    const float* attn_in_b  = (const float*)d_in[14];
    const float* attn_out_w = (const float*)d_in[15];
    const float* attn_out_b = (const float*)d_in[16];
    const float* mlp_w1     = (const float*)d_in[17];
    const float* mlp_b1     = (const float*)d_in[18];
    const float* mlp_w2     = (const float*)d_in[19];
    const float* mlp_b2     = (const float*)d_in[20];
    const float* gum        = (const float*)d_in[21];

    float* adj = (float*)d_out;
    hipMemsetAsync(adj, 0, (size_t)out_size * sizeof(float), stream);

    const size_t NEED = 262144000;
    if (ws_size < NEED) { hipLaunchKernelGGL(k_ws_too_small, dim3(1), dim3(1), 0, stream, adj); return; }

    // Region map (phase-aliased):
    //  A [0,157286400): xg f64  | post-GRU: ne f32 @0, QKV f32 @26214400,
    //                             G0 @104857600, G1 @131072000
    //  B [157286400,209715200): seq f64 -> h0 f64 -> wP1 -> h1m f64
    //                           -> cbf f64 @ +0, VW scratch f32 @ +4096
    //  C [209715200,262144000): wP0 -> h1 f64 -> G2 @ +0, G3 @ +26214400
    char* ws = (char*)d_ws;
    double* xg   = (double*)(ws);
    double* seqB = (double*)(ws + 157286400);
    double* h0   = (double*)(ws + 157286400);
    float*  wP1  = (float*)(ws + 157286400);
    double* h1m  = (double*)(ws + 157286400);
    double* cbf  = (double*)(ws + 157286400);
    float*  VWs  = (float*)(ws + 157286400 + 4096);
    float*  wP0  = (float*)(ws + 209715200);
    double* h1   = (double*)(ws + 209715200);
    float*  ne   = (float*)(ws);
    float*  qkv  = (float*)(ws + 26214400);
    float*  Gh[4] = { (float*)(ws + 104857600), (float*)(ws + 131072000),
                      (float*)(ws + 209715200), (float*)(ws + 209715200 + 26214400) };

    // 1) seq + layer-0 input gates
    hipLaunchKernelGGL(k_seq, dim3(12800), dim3(256), 0, stream, z, pos, nn, seqB);
    hipLaunchKernelGGL((k_gemm<LATENT, true, true, true>), dim3(400, 6), dim3(256), 0, stream,
                       (const void*)seqB, (long)LATENT, w_ih0, LATENT, 0, b_ih0,
                       (void*)xg, (long)GDIM, 0);
    // 2) GRU layer 0
    hipLaunchKernelGGL(k_pack, dim3(768), dim3(256), 0, stream, w_hh0, wP0);
    for (int t = 0; t < NMAX; ++t)
        hipLaunchKernelGGL(k_gru_step3, dim3(256), dim3(256), 0, stream, xg, h0, wP0, b_hh0, t);
    // 3) layer-1 input gates
    hipLaunchKernelGGL((k_gemm<HID, true, true, true>), dim3(400, 6), dim3(256), 0, stream,
                       (const void*)h0, (long)HID, w_ih1, HID, 0, b_ih1,
                       (void*)xg, (long)GDIM, 0);
    // 4) GRU layer 1
    hipLaunchKernelGGL(k_pack, dim3(768), dim3(256), 0, stream, w_hh1, wP1);
    for (int t = 0; t < NMAX; ++t)
        hipLaunchKernelGGL(k_gru_step3, dim3(256), dim3(256), 0, stream, xg, h1, wP1, b_hh1, t);
    // 5) mask, node_emb, qkv
    hipLaunchKernelGGL(k_maskh, dim3(25600), dim3(256), 0, stream, h1, nn, h1m);
    hipLaunchKernelGGL((k_gemm<HID, true, false, false>), dim3(400, 2), dim3(256), 0, stream,
                       (const void*)h1m, (long)HID, proj, HID, 0, (const float*)nullptr,
                       (void*)ne, (long)HID, 0);
    hipLaunchKernelGGL(k_const, dim3(1), dim3(256), 0, stream, attn_out_b, mlp_w1, mlp_b1, cbf);
    hipLaunchKernelGGL((k_gemm<HID, false, false, true>), dim3(400, 6), dim3(256), 0, stream,
                       (const void*)ne, (long)HID, attn_in_w, HID, 0, attn_in_b,
                       (void*)qkv, (long)GDIM, 0);
    // 6) per-head VW then G
    for (int h = 0; h < NHEADS; ++h) {
        hipLaunchKernelGGL((k_gemm<HD, false, false, false>), dim3(400, 2), dim3(256), 0, stream,
                           (const void*)(qkv + 2 * HID + h * HD), (long)GDIM,
                           attn_out_w, HID, h * HD, (const float*)nullptr,
                           (void*)VWs, (long)HID, 0);
        hipLaunchKernelGGL((k_gemm<HID, false, false, false>), dim3(400, 2), dim3(256), 0, stream,
                           (const void*)VWs, (long)HID, mlp_w1, HID, 0, (const float*)nullptr,
                           (void*)Gh[h], (long)HID, 0);
    }
    // 7) pairs
    hipLaunchKernelGGL(k_pairs2, dim3(BB * (NMAX - 1)), dim3(256), 0, stream,
                       qkv, Gh[0], Gh[1], Gh[2], Gh[3], cbf, nn, gum, mlp_w2, mlp_b2, adj);
}

// Round 4
// 3628.366 us; speedup vs baseline: 2.1747x; 1.1132x over previous
//
#include <hip/hip_runtime.h>
#include <hip/hip_bf16.h>
#include <math.h>

#define BB 512
#define LATENT 128
#define HID 256
#define GDIM 768
#define NMAX 50
#define NHEADS 4
#define HD 64
#define NPAIRS 1225

// ---------------------------------------------------------------------------
// Tiled GEMM: O[r][oc] = sum_k X[r][k] * W[oc][k] (+bias[oc])
// Block tile 128x128, 256 threads, thread tile 8x8, f64 accumulate.
// Conflict-free LDS: row length 17 (odd), compute col = j*16+tx.
// XMODE: 0 = plain X pointer (f64 if XF64 else f32)
//        1 = X[row][k] = (t<nn[b]) ? z[b][k]+pos[t][k] : 0   (row=b*50+t, f64)
//        2 = X f64 with row mask (n<nn[b])
// blockIdx.z with element offsets xzoff (X col), wzoff (W elems), ozoff (out col).
template<int KD, int XMODE, bool XF64, bool OF64, bool BIAS>
__global__ __launch_bounds__(256) void k_gemm2(
        const void* __restrict__ Xv, long xstride, int xzoff,
        const float* __restrict__ zin, const float* __restrict__ pin,
        const int* __restrict__ nn,
        const float* __restrict__ W, int wstride, long wzoff,
        const float* __restrict__ bias,
        void* __restrict__ Ov, long ostride, int ozoff)
{
    __shared__ double xs[128][17];
    __shared__ float  wsm[128][17];
    const int rb = blockIdx.x * 128;
    const int ob = blockIdx.y * 128;
    const int zid = blockIdx.z;
    const int tid = threadIdx.x;
    const int ty = tid >> 4, tx = tid & 15;

    // loader mapping
    const int lr  = tid >> 1;            // 0..127 (X row / W row)
    const int lk  = (tid & 1) * 8;       // k offset 0/8
    const int xrow = rb + lr;

    bool maskv = true;
    const float* zp = nullptr; const float* pp = nullptr;
    const double* xp64 = nullptr; const float* xp32 = nullptr;
    if (XMODE == 1) {
        int b = xrow / NMAX, t = xrow % NMAX;
        maskv = t < nn[b];
        zp = zin + (size_t)b * LATENT;
        pp = pin + (size_t)t * LATENT;
    } else if (XMODE == 2) {
        int b = xrow / NMAX, t = xrow % NMAX;
        maskv = t < nn[b];
        xp64 = (const double*)Xv + (size_t)xrow * xstride + zid * (long)xzoff;
    } else {
        if (XF64) xp64 = (const double*)Xv + (size_t)xrow * xstride + zid * (long)xzoff;
        else      xp32 = (const float*)Xv + (size_t)xrow * xstride + zid * (long)xzoff;
    }
    const float* wp = W + (size_t)zid * wzoff + (size_t)(ob + lr) * wstride + lk;

    double acc[8][8];
    #pragma unroll
    for (int i = 0; i < 8; ++i)
        #pragma unroll
        for (int j = 0; j < 8; ++j) acc[i][j] = 0.0;

    for (int k0 = 0; k0 < KD; k0 += 16) {
        // stage X tile
        if (XMODE == 1) {
            #pragma unroll
            for (int u = 0; u < 8; ++u)
                xs[lr][lk + u] = maskv ? (double)zp[k0 + lk + u] + (double)pp[k0 + lk + u] : 0.0;
        } else if (XMODE == 2) {
            #pragma unroll
            for (int u = 0; u < 8; ++u)
                xs[lr][lk + u] = maskv ? xp64[k0 + lk + u] : 0.0;
        } else if (XF64) {
            #pragma unroll
            for (int u = 0; u < 8; ++u) xs[lr][lk + u] = xp64[k0 + lk + u];
        } else {
            #pragma unroll
            for (int u = 0; u < 8; ++u) xs[lr][lk + u] = (double)xp32[k0 + lk + u];
        }
        // stage W tile
        #pragma unroll
        for (int u = 0; u < 8; ++u) wsm[lr][lk + u] = wp[k0 + u];
        __syncthreads();
        #pragma unroll
        for (int kk = 0; kk < 16; ++kk) {
            double wv[8];
            #pragma unroll
            for (int j = 0; j < 8; ++j) wv[j] = (double)wsm[j * 16 + tx][kk];
            #pragma unroll
            for (int i = 0; i < 8; ++i) {
                double xr = xs[ty * 8 + i][kk];
                #pragma unroll
                for (int j = 0; j < 8; ++j) acc[i][j] += xr * wv[j];
            }
        }
        __syncthreads();
    }
    #pragma unroll
    for (int i = 0; i < 8; ++i) {
        size_t row = rb + ty * 8 + i;
        #pragma unroll
        for (int j = 0; j < 8; ++j) {
            int ocg = ob + j * 16 + tx;
            double v = acc[i][j];
            if (BIAS) v += (double)bias[ocg];
            size_t o = row * ostride + (size_t)zid * ozoff + ocg;
            if (OF64) ((double*)Ov)[o] = v;
            else      ((float*)Ov)[o] = (float)v;
        }
    }
}

// ---------------------------------------------------------------------------
// pack w_hh [768][256] -> wP2[fs(4)][k(256)][g(3)*64+f]
__global__ __launch_bounds__(256) void k_pack2(
        const float* __restrict__ whh, float* __restrict__ wP)
{
    int idx = blockIdx.x * 256 + threadIdx.x;   // 196608
    int srow = idx >> 8, k = idx & 255;
    int g = srow >> 8, ff = srow & 255;
    int fs = ff >> 6, f = ff & 63;
    wP[((size_t)fs * HID + k) * 192 + g * 64 + f] = whh[(size_t)srow * HID + k];
}

// ---------------------------------------------------------------------------
// GRU step: grid 256 = 64 bgroups(8 rows) x 4 fslices(64 feats).
// thread = r(8) x fp(32); features fp, fp+32 of slice; double-buffered weights.
__global__ __launch_bounds__(256) void k_gru_step4(
        const double* __restrict__ xg, double* __restrict__ hout,
        const float* __restrict__ wP, const float* __restrict__ bhh, int t)
{
    const int bg = blockIdx.x >> 2;
    const int fs = blockIdx.x & 3;
    const int b0 = bg << 3;
    const int r  = threadIdx.x >> 5;
    const int fp = threadIdx.x & 31;
    __shared__ double hs[8][HID];
    __shared__ float  wt[2][32][192];

    for (int idx = threadIdx.x; idx < 8 * HID; idx += 256) {
        int rr = idx >> 8, k = idx & 255;
        hs[rr][k] = (t == 0) ? 0.0
                  : hout[((size_t)(b0 + rr) * NMAX + (t - 1)) * HID + k];
    }
    const float4* wbase = (const float4*)(wP + (size_t)fs * HID * 192);
    float4 stg[6];
    #pragma unroll
    for (int u = 0; u < 6; ++u) stg[u] = wbase[threadIdx.x + 256 * u];
    {
        float4* dst = (float4*)&wt[0][0][0];
        #pragma unroll
        for (int u = 0; u < 6; ++u) dst[threadIdx.x + 256 * u] = stg[u];
    }
    __syncthreads();

    double a[6] = {0, 0, 0, 0, 0, 0};
    for (int c = 0; c < 8; ++c) {
        if (c < 7) {
            const float4* src = wbase + (size_t)(c + 1) * 1536;
            #pragma unroll
            for (int u = 0; u < 6; ++u) stg[u] = src[threadIdx.x + 256 * u];
        }
        const int k0 = c * 32;
        #pragma unroll 4
        for (int kk = 0; kk < 32; ++kk) {
            double hk = hs[r][k0 + kk];
            const float* wrow = &wt[c & 1][kk][0];
            a[0] += hk * (double)wrow[fp];
            a[1] += hk * (double)wrow[fp + 32];
            a[2] += hk * (double)wrow[64 + fp];
            a[3] += hk * (double)wrow[64 + fp + 32];
            a[4] += hk * (double)wrow[128 + fp];
            a[5] += hk * (double)wrow[128 + fp + 32];
        }
        __syncthreads();
        if (c < 7) {
            float4* dst = (float4*)&wt[(c + 1) & 1][0][0];
            #pragma unroll
            for (int u = 0; u < 6; ++u) dst[threadIdx.x + 256 * u] = stg[u];
            __syncthreads();
        }
    }
    const int b = b0 + r;
    const double* x = xg + ((size_t)b * NMAX + t) * GDIM;
    double* hp = hout + ((size_t)b * NMAX + t) * HID;
    const int fbase = fs * 64;
    #pragma unroll
    for (int e = 0; e < 2; ++e) {
        int f = fbase + fp + e * 32;
        double hr = a[0 + e] + (double)bhh[f];
        double hz = a[2 + e] + (double)bhh[HID + f];
        double hn = a[4 + e] + (double)bhh[2 * HID + f];
        double rg = 1.0 / (1.0 + exp(-(x[f] + hr)));
        double zg = 1.0 / (1.0 + exp(-(x[HID + f] + hz)));
        double ng = tanh(x[2 * HID + f] + rg * hn);
        hp[f] = (1.0 - zg) * ng + zg * hs[r][f];
    }
}

// ---------------------------------------------------------------------------
// WQ[g][h] = sum_o attn_in_w[g][o] * proj[o][h]   (768x256 f32)
__global__ __launch_bounds__(256) void k_wq(
        const float* __restrict__ aiw, const float* __restrict__ proj,
        float* __restrict__ WQ)
{
    __shared__ float arow[HID];
    int g = blockIdx.x, h = threadIdx.x;
    arow[h] = aiw[(size_t)g * HID + h];
    __syncthreads();
    double acc = 0.0;
    for (int o = 0; o < HID; ++o) acc += (double)arow[o] * (double)proj[(size_t)o * HID + h];
    WQ[(size_t)g * HID + h] = (float)acc;
}

// ---------------------------------------------------------------------------
// M[h][k][d] = sum_m wo[m][h*64+d] * w1[k][m]   (4x256x64 f32)
__global__ __launch_bounds__(256) void k_m(
        const float* __restrict__ wo, const float* __restrict__ w1,
        float* __restrict__ M)
{
    __shared__ float w1row[HID];
    int k = blockIdx.x, hd = threadIdx.x;
    w1row[hd] = w1[(size_t)k * HID + hd];
    __syncthreads();
    double acc = 0.0;
    for (int m = 0; m < HID; ++m) acc += (double)w1row[m] * (double)wo[(size_t)m * HID + hd];
    M[(((size_t)(hd >> 6)) * HID + k) * HD + (hd & 63)] = (float)acc;
}

// ---------------------------------------------------------------------------
// c[k] = sum_m attn_out_b[m]*mlp_w1[k,m] + mlp_b1[k]
__global__ void k_const(const float* __restrict__ ob, const float* __restrict__ w1,
                        const float* __restrict__ b1, double* __restrict__ c)
{
    int k = threadIdx.x;
    double acc = 0.0;
    for (int m = 0; m < HID; ++m) acc += (double)ob[m] * (double)w1[k * HID + m];
    c[k] = acc + (double)b1[k];
}

// ---------------------------------------------------------------------------
// Pairs: block per (b,i); wave per j (stride 4). G unified [row][h*256+k].
__global__ __launch_bounds__(256) void k_pairs3(
        const float* __restrict__ QKV, const float* __restrict__ G,
        const double* __restrict__ c,
        const int* __restrict__ nn, const float* __restrict__ gum,
        const float* __restrict__ w2, const float* __restrict__ b2,
        float* __restrict__ adj)
{
    const int bi = blockIdx.x;
    const int b = bi / (NMAX - 1);
    const int i = bi % (NMAX - 1);
    const int nnb = nn[b];
    if (i >= nnb - 1) return;
    const int tid = threadIdx.x;
    const int lane = tid & 63;
    const int wave = tid >> 6;
    const size_t rowi = (size_t)b * NMAX + i;

    double cw[4], w2r[4];
    float gir[4][4];
    #pragma unroll
    for (int q = 0; q < 4; ++q) {
        int k = lane + 64 * q;
        cw[q] = c[k];
        w2r[q] = (double)w2[k] - (double)w2[HID + k];
        #pragma unroll
        for (int h = 0; h < 4; ++h) gir[q][h] = G[rowi * 1024 + h * HID + k];
    }
    const int sh = lane >> 4, sd = (lane & 15) * 4;
    const float4 qv  = *(const float4*)&QKV[rowi * GDIM + sh * HD + sd];
    const float4 kv0 = *(const float4*)&QKV[rowi * GDIM + HID + sh * HD + sd];
    double s0 = (double)qv.x * kv0.x + (double)qv.y * kv0.y
              + (double)qv.z * kv0.z + (double)qv.w * kv0.w;
    #pragma unroll
    for (int m = 1; m < 16; m <<= 1) s0 += __shfl_xor(s0, m, 64);
    s0 *= 0.125;
    const double b2d = (double)b2[0] - (double)b2[1];

    for (int j = i + 1 + wave; j < nnb; j += 4) {
        const size_t rowj = (size_t)b * NMAX + j;
        const float4 kv = *(const float4*)&QKV[rowj * GDIM + HID + sh * HD + sd];
        double s1 = (double)qv.x * kv.x + (double)qv.y * kv.y
                  + (double)qv.z * kv.z + (double)qv.w * kv.w;
        #pragma unroll
        for (int m = 1; m < 16; m <<= 1) s1 += __shfl_xor(s1, m, 64);
        s1 *= 0.125;
        double mx = fmax(s0, s1);
        double e0 = exp(s0 - mx), e1 = exp(s1 - mx);
        double inv = 1.0 / (e0 + e1);
        double a0 = e0 * inv, a1 = e1 * inv;
        double a0h[4], a1h[4];
        #pragma unroll
        for (int h = 0; h < 4; ++h) {
            a0h[h] = __shfl(a0, h * 16, 64);
            a1h[h] = __shfl(a1, h * 16, 64);
        }
        double dsum = 0.0;
        #pragma unroll
        for (int q = 0; q < 4; ++q) {
            int k = lane + 64 * q;
            double pre = cw[q];
            #pragma unroll
            for (int h = 0; h < 4; ++h)
                pre += a0h[h] * (double)gir[q][h]
                     + a1h[h] * (double)G[rowj * 1024 + h * HID + k];
            if (pre > 0.0) dsum += pre * w2r[q];
        }
        #pragma unroll
        for (int m = 1; m < 64; m <<= 1) dsum += __shfl_xor(dsum, m, 64);
        if (lane == 0) {
            int p_idx = i * (2 * NMAX - i - 1) / 2 + (j - i - 1);
            const float* gp = gum + ((size_t)b * NPAIRS + p_idx) * 2;
            double d = dsum + b2d + (double)gp[0] - (double)gp[1];
            if (d >= 0.0) {
                adj[(size_t)b * NMAX * NMAX + i * NMAX + j] = 1.0f;
                adj[(size_t)b * NMAX * NMAX + j * NMAX + i] = 1.0f;
            }
        }
    }
}

__global__ void k_ws_too_small(float* adj) { adj[0] = 2.0f; }

// ---------------------------------------------------------------------------
extern "C" void kernel_launch(void* const* d_in, const int* in_sizes, int n_in,
                              void* d_out, int out_size, void* d_ws, size_t ws_size,
                              hipStream_t stream)
{
    const float* z          = (const float*)d_in[0];
    const int*   nn         = (const int*)d_in[1];
    const float* pos        = (const float*)d_in[3];
    const float* w_ih0      = (const float*)d_in[4];
    const float* w_hh0      = (const float*)d_in[5];
    const float* b_ih0      = (const float*)d_in[6];
    const float* b_hh0      = (const float*)d_in[7];
    const float* w_ih1      = (const float*)d_in[8];
    const float* w_hh1      = (const float*)d_in[9];
    const float* b_ih1      = (const float*)d_in[10];
    const float* b_hh1      = (const float*)d_in[11];
    const float* proj       = (const float*)d_in[12];
    const float* attn_in_w  = (const float*)d_in[13];
    const float* attn_in_b  = (const float*)d_in[14];
    const float* attn_out_w = (const float*)d_in[15];
    const float* attn_out_b = (const float*)d_in[16];
    const float* mlp_w1     = (const float*)d_in[17];
    const float* mlp_b1     = (const float*)d_in[18];
    const float* mlp_w2     = (const float*)d_in[19];
    const float* mlp_b2     = (const float*)d_in[20];
    const float* gum        = (const float*)d_in[21];

    float* adj = (float*)d_out;
    hipMemsetAsync(adj, 0, (size_t)out_size * sizeof(float), stream);

    const size_t NEED = 262144000;
    if (ws_size < NEED) { hipLaunchKernelGGL(k_ws_too_small, dim3(1), dim3(1), 0, stream, adj); return; }

    // Region map (phase-aliased; all on one stream => sequential hazards OK):
    //  A [0,157286400): xg f64          | post: qkv f32 @0 (78.6MB), G f32 @78643200 (104.9MB,
    //                                     spills 26.2MB into dead B)
    //  B [157286400,209715200): h0 f64 -> wP1 @+0 -> WQ @+0 (dead once G written)
    //  C [209715200,262144000): wP0 @+0 -> h1 f64 @+0 -> M @261619712, cbf @261881856
    char* ws = (char*)d_ws;
    double* xg  = (double*)(ws);
    double* h0  = (double*)(ws + 157286400);
    float*  wP1 = (float*)(ws + 157286400);
    float*  WQ  = (float*)(ws + 157286400);
    float*  wP0 = (float*)(ws + 209715200);
    double* h1  = (double*)(ws + 209715200);
    float*  qkv = (float*)(ws);
    float*  G   = (float*)(ws + 78643200);
    float*  M   = (float*)(ws + 261619712);
    double* cbf = (double*)(ws + 261881856);

    // 1) fused seq construction + layer-0 input gates
    hipLaunchKernelGGL((k_gemm2<LATENT, 1, true, true, true>), dim3(200, 6), dim3(256), 0, stream,
                       nullptr, 0L, 0, z, pos, nn, w_ih0, LATENT, 0L, b_ih0,
                       (void*)xg, (long)GDIM, 0);
    // 2) GRU layer 0
    hipLaunchKernelGGL(k_pack2, dim3(768), dim3(256), 0, stream, w_hh0, wP0);
    for (int t = 0; t < NMAX; ++t)
        hipLaunchKernelGGL(k_gru_step4, dim3(256), dim3(256), 0, stream, xg, h0, wP0, b_hh0, t);
    // 3) layer-1 input gates
    hipLaunchKernelGGL((k_gemm2<HID, 0, true, true, true>), dim3(200, 6), dim3(256), 0, stream,
                       (const void*)h0, (long)HID, 0, nullptr, nullptr, nn,
                       w_ih1, HID, 0L, b_ih1, (void*)xg, (long)GDIM, 0);
    // 4) GRU layer 1 (wP1 overwrites dead h0)
    hipLaunchKernelGGL(k_pack2, dim3(768), dim3(256), 0, stream, w_hh1, wP1);
    for (int t = 0; t < NMAX; ++t)
        hipLaunchKernelGGL(k_gru_step4, dim3(256), dim3(256), 0, stream, xg, h1, wP1, b_hh1, t);
    // 5) fused (proj @ attn_in_w) then masked qkv directly from h1
    hipLaunchKernelGGL(k_wq, dim3(768), dim3(256), 0, stream, attn_in_w, proj, WQ);
    hipLaunchKernelGGL((k_gemm2<HID, 2, true, false, true>), dim3(200, 6), dim3(256), 0, stream,
                       (const void*)h1, (long)HID, 0, nullptr, nullptr, nn,
                       WQ, HID, 0L, attn_in_b, (void*)qkv, (long)GDIM, 0);
    // 6) M precompute + single fused G GEMM (grid.z = head)
    hipLaunchKernelGGL(k_m, dim3(256), dim3(256), 0, stream, attn_out_w, mlp_w1, M);
    hipLaunchKernelGGL(k_const, dim3(1), dim3(256), 0, stream, attn_out_b, mlp_w1, mlp_b1, cbf);
    hipLaunchKernelGGL((k_gemm2<HD, 0, false, false, false>), dim3(200, 2, 4), dim3(256), 0, stream,
                       (const void*)(qkv + 2 * HID), (long)GDIM, HD, nullptr, nullptr, nn,
                       M, HD, (long)(HID * HD), (const float*)nullptr,
                       (void*)G, 1024L, HID);
    // 7) pairs
    hipLaunchKernelGGL(k_pairs3, dim3(BB * (NMAX - 1)), dim3(256), 0, stream,
                       qkv, G, cbf, nn, gum, mlp_w2, mlp_b2, adj);
}